// Round 8
// baseline (240.399 us; speedup 1.0000x reference)
//
#include <hip/hip_runtime.h>

#define BATCH 512
#define NN    200
#define SIG1  0.73105857863f   // sigmoid(1)
#define SIG0  0.5f             // sigmoid(0)

// ---------------------------------------------------------------------------
// prep: blocks 0..156: Rs[n][m] = 0.5*(R[n][m]+R[m][n]) + (n==m)   (fp32)
//       block 157:     Wc = W0 @ (W1 @ (W2 @ pw))   [200][2] fp32
__global__ __launch_bounds__(256) void prep(
    const float* __restrict__ R,
    const float* __restrict__ W0, const float* __restrict__ W1,
    const float* __restrict__ W2, const float* __restrict__ pw,
    float* __restrict__ Rs, float* __restrict__ Wc) {
    const int blk = blockIdx.x;
    const int tid = threadIdx.x;
    if (blk < 157) {
        int idx = blk * 256 + tid;
        if (idx < NN * NN) {
            int n = idx / NN, m = idx - n * NN;
            Rs[idx] = 0.5f * (R[idx] + R[m * NN + n]) + (n == m ? 1.f : 0.f);
        }
    } else {
        __shared__ float t0[256], t1[256];
        float a0 = 0.f, a1 = 0.f;
#pragma unroll 16
        for (int c = 0; c < 256; ++c) {
            float w2 = W2[tid * 256 + c];
            a0 += w2 * pw[2 * c];
            a1 += w2 * pw[2 * c + 1];
        }
        t0[tid] = a0; t1[tid] = a1;
        __syncthreads();
        float b0 = 0.f, b1 = 0.f;
#pragma unroll 16
        for (int h = 0; h < 256; ++h) {
            float w1 = W1[tid * 256 + h];
            b0 += w1 * t0[h];
            b1 += w1 * t1[h];
        }
        __syncthreads();
        t0[tid] = b0; t1[tid] = b1;
        __syncthreads();
        if (tid < NN) {
            float c0 = 0.f, c1 = 0.f;
#pragma unroll 16
            for (int o = 0; o < 256; ++o) {
                float w0 = W0[tid * 256 + o];
                c0 += w0 * t0[o];
                c1 += w0 * t1[o];
            }
            Wc[tid * 2 + 0] = c0;
            Wc[tid * 2 + 1] = c1;
        }
    }
}

// ---------------------------------------------------------------------------
// K1: stream adj once. Thread (q = tid>>6 in [0,8), c4 = tid&63, cc=min(c4,49)):
// rows n = 25q..25q+24 (fixed trip), cols [4cc,4cc+4).
// Writes: up[b][q][m] partial col-sums of M (float4), packed bits (uint4).
__global__ __launch_bounds__(512, 8) void scan_adj(
    const float* __restrict__ adj, const float* __restrict__ Rs,
    float* __restrict__ up, uint* __restrict__ bitws) {
    const int b = blockIdx.x;
    const int tid = threadIdx.x;
    const int c4 = tid & 63;
    const int q  = tid >> 6;
    const int cc = (c4 < 50) ? c4 : 49;
    const int col0 = cc * 4;
    const int n0 = q * 25;
    const float* adjb = adj + (size_t)b * NN * NN;

    uint m0 = 0, m1 = 0, m2 = 0, m3 = 0;
    float4 acc = {0.f, 0.f, 0.f, 0.f};
#pragma unroll 5
    for (int j = 0; j < 25; ++j) {
        int n = n0 + j;
        float4 a = *(const float4*)(adjb + n * NN + col0);
        float4 r = *(const float4*)(Rs   + n * NN + col0);
        bool t;
        t = a.x > 0.5f; m0 |= (uint)t << j; acc.x += r.x * (t ? SIG1 : SIG0);
        t = a.y > 0.5f; m1 |= (uint)t << j; acc.y += r.y * (t ? SIG1 : SIG0);
        t = a.z > 0.5f; m2 |= (uint)t << j; acc.z += r.z * (t ? SIG1 : SIG0);
        t = a.w > 0.5f; m3 |= (uint)t << j; acc.w += r.w * (t ? SIG1 : SIG0);
    }
    if (c4 < 50) {
        *(float4*)(up + ((size_t)(b * 8 + q)) * NN + col0) = acc;
        uint4 mb; mb.x = m0; mb.y = m1; mb.z = m2; mb.w = m3;
        *(uint4*)(bitws + ((size_t)(b * 8 + q) * 50 + cc) * 4) = mb;
    }
}

// ---------------------------------------------------------------------------
// K2: all-cache solve. Same (q,c4) partition.
//   u = sum_q up ; v = M^T u ; w = M^T v ; y = X^T w ; out = (y·Wc)/N + pb
__global__ __launch_bounds__(512, 8) void solve(
    const float* __restrict__ feat, const float* __restrict__ Rs,
    const float* __restrict__ up, const uint* __restrict__ bitws,
    const float* __restrict__ Wc, const float* __restrict__ pb,
    float* __restrict__ out) {
    const int b = blockIdx.x;
    const int tid = threadIdx.x;
    const int c4 = tid & 63;
    const int q  = tid >> 6;
    const int cc = (c4 < 50) ? c4 : 49;
    const int col0 = cc * 4;
    const int n0 = q * 25;
    const float* featb = feat + (size_t)b * NN * NN;
    __shared__ float4 us[512];
    __shared__ float xs[NN];

    // load this thread's packed bits (one uint4)
    uint4 mb = *(const uint4*)(bitws + ((size_t)(b * 8 + q) * 50 + cc) * 4);

    // u = sum over q of up partials
    float4 z = {0.f, 0.f, 0.f, 0.f};
    us[tid] = (c4 < 50) ? *(const float4*)(up + ((size_t)(b * 8 + q)) * NN + col0) : z;
    __syncthreads();
    if (tid < 64) {
        float4 s = us[tid];
#pragma unroll
        for (int qq = 1; qq < 8; ++qq) {
            float4 p = us[qq * 64 + tid];
            s.x += p.x; s.y += p.y; s.z += p.z; s.w += p.w;
        }
        if (tid < 50) {
            xs[tid * 4 + 0] = s.x; xs[tid * 4 + 1] = s.y;
            xs[tid * 4 + 2] = s.z; xs[tid * 4 + 3] = s.w;
        }
    }
    __syncthreads();

    // Phase B: v = M^T u
    float4 acc = z;
#pragma unroll 5
    for (int j = 0; j < 25; ++j) {
        int n = n0 + j;
        float4 r = *(const float4*)(Rs + n * NN + col0);
        float xn = xs[n];
        acc.x += r.x * (((mb.x >> j) & 1u) ? SIG1 : SIG0) * xn;
        acc.y += r.y * (((mb.y >> j) & 1u) ? SIG1 : SIG0) * xn;
        acc.z += r.z * (((mb.z >> j) & 1u) ? SIG1 : SIG0) * xn;
        acc.w += r.w * (((mb.w >> j) & 1u) ? SIG1 : SIG0) * xn;
    }
    us[tid] = acc;
    __syncthreads();
    if (tid < 64) {
        float4 s = us[tid];
#pragma unroll
        for (int qq = 1; qq < 8; ++qq) {
            float4 p = us[qq * 64 + tid];
            s.x += p.x; s.y += p.y; s.z += p.z; s.w += p.w;
        }
        if (tid < 50) {
            xs[tid * 4 + 0] = s.x; xs[tid * 4 + 1] = s.y;
            xs[tid * 4 + 2] = s.z; xs[tid * 4 + 3] = s.w;
        }
    }
    __syncthreads();

    // Phase C: w = M^T v
    acc = z;
#pragma unroll 5
    for (int j = 0; j < 25; ++j) {
        int n = n0 + j;
        float4 r = *(const float4*)(Rs + n * NN + col0);
        float xn = xs[n];
        acc.x += r.x * (((mb.x >> j) & 1u) ? SIG1 : SIG0) * xn;
        acc.y += r.y * (((mb.y >> j) & 1u) ? SIG1 : SIG0) * xn;
        acc.z += r.z * (((mb.z >> j) & 1u) ? SIG1 : SIG0) * xn;
        acc.w += r.w * (((mb.w >> j) & 1u) ? SIG1 : SIG0) * xn;
    }
    us[tid] = acc;
    __syncthreads();
    if (tid < 64) {
        float4 s = us[tid];
#pragma unroll
        for (int qq = 1; qq < 8; ++qq) {
            float4 p = us[qq * 64 + tid];
            s.x += p.x; s.y += p.y; s.z += p.z; s.w += p.w;
        }
        if (tid < 50) {
            xs[tid * 4 + 0] = s.x; xs[tid * 4 + 1] = s.y;
            xs[tid * 4 + 2] = s.z; xs[tid * 4 + 3] = s.w;
        }
    }
    __syncthreads();

    // Phase D: y partial over this slice's feat rows
    acc = z;
#pragma unroll 5
    for (int j = 0; j < 25; ++j) {
        int n = n0 + j;
        float4 f = *(const float4*)(featb + n * NN + col0);
        float xn = xs[n];
        acc.x += f.x * xn; acc.y += f.y * xn;
        acc.z += f.z * xn; acc.w += f.w * xn;
    }
    us[tid] = acc;
    __syncthreads();

    // Final: combine y, dot with Wc, wave-reduce, write
    if (tid < 64) {
        float4 s = us[tid];
#pragma unroll
        for (int qq = 1; qq < 8; ++qq) {
            float4 p = us[qq * 64 + tid];
            s.x += p.x; s.y += p.y; s.z += p.z; s.w += p.w;
        }
        float p0 = 0.f, p1 = 0.f;
        if (tid < 50) {
            int ci = tid * 4;
            p0 = s.x * Wc[(ci + 0) * 2] + s.y * Wc[(ci + 1) * 2]
               + s.z * Wc[(ci + 2) * 2] + s.w * Wc[(ci + 3) * 2];
            p1 = s.x * Wc[(ci + 0) * 2 + 1] + s.y * Wc[(ci + 1) * 2 + 1]
               + s.z * Wc[(ci + 2) * 2 + 1] + s.w * Wc[(ci + 3) * 2 + 1];
        }
#pragma unroll
        for (int off = 32; off > 0; off >>= 1) {
            p0 += __shfl_down(p0, off);
            p1 += __shfl_down(p1, off);
        }
        if (tid == 0) {
            out[b * 2 + 0] = p0 * (1.f / NN) + pb[0];
            out[b * 2 + 1] = p1 * (1.f / NN) + pb[1];
        }
    }
}

// ---------------------------------------------------------------------------
extern "C" void kernel_launch(void* const* d_in, const int* in_sizes, int n_in,
                              void* d_out, int out_size, void* d_ws, size_t ws_size,
                              hipStream_t stream) {
    const float* adj  = (const float*)d_in[0];
    const float* feat = (const float*)d_in[1];
    const float* R    = (const float*)d_in[2];
    const float* W0   = (const float*)d_in[3];
    const float* W1   = (const float*)d_in[4];
    const float* W2   = (const float*)d_in[5];
    const float* pw   = (const float*)d_in[6];
    const float* pb   = (const float*)d_in[7];

    char* ws = (char*)d_ws;
    float* Rs    = (float*)(ws);               // 160,000 B
    float* Wc    = (float*)(ws + 160000);      // 1,600 B
    float* up    = (float*)(ws + 163840);      // 512*8*200*4 = 3,276,800 B
    uint*  bitws = (uint*)(ws + 3440640);      // 512*8*50*16 = 3,276,800 B

    prep<<<158, 256, 0, stream>>>(R, W0, W1, W2, pw, Rs, Wc);
    scan_adj<<<BATCH, 512, 0, stream>>>(adj, Rs, up, bitws);
    solve<<<BATCH, 512, 0, stream>>>(feat, Rs, up, bitws, Wc, pb, (float*)d_out);
}